// Round 16
// baseline (252.600 us; speedup 1.0000x reference)
//
#include <hip/hip_runtime.h>
#include <cstdint>
#include <cstddef>

// Problem constants: b=2,s=32 -> BS=64; c=128; h=w=24 -> L=576
constexpr int BS   = 64;
constexpr int Cc   = 128;
constexpr int Lc   = 576;
constexpr int VD   = 128;   // v dim per head
constexpr int HID  = 256;
constexpr int OUTC = 128;
constexpr int NPIX = BS * Lc;  // 36864

typedef __bf16 bf16x8 __attribute__((ext_vector_type(8)));
typedef float  f32x4  __attribute__((ext_vector_type(4)));
typedef unsigned short u16x8 __attribute__((ext_vector_type(8)));
typedef unsigned int   u32x4 __attribute__((ext_vector_type(4)));

__device__ __forceinline__ unsigned short f2bf(float f) {
  unsigned int u = __builtin_bit_cast(unsigned int, f);
  u += 0x7fffu + ((u >> 16) & 1u);   // RTNE (inputs finite)
  return (unsigned short)(u >> 16);
}
__device__ __forceinline__ float bf2f(unsigned short h) {
  unsigned int u = ((unsigned int)h) << 16;
  return __builtin_bit_cast(float, u);
}
// pack value as hi-bf16 (bits 31:16) | lo-bf16 (bits 15:0), lo = residual
__device__ __forceinline__ unsigned int packhl(float v) {
  unsigned short hi = f2bf(v);
  unsigned short lo = f2bf(v - bf2f(hi));
  return ((unsigned int)hi << 16) | (unsigned int)lo;
}
// unpack 8 packed elements (two 16B u32x4 loads) -> hi/lo bf16x8 fragments
__device__ __forceinline__ void unpack8(u32x4 a, u32x4 b, bf16x8& hi, bf16x8& lo) {
  u32x4 h, l;
  h[0] = (a[1] & 0xffff0000u) | (a[0] >> 16);
  l[0] = (a[1] << 16)         | (a[0] & 0xffffu);
  h[1] = (a[3] & 0xffff0000u) | (a[2] >> 16);
  l[1] = (a[3] << 16)         | (a[2] & 0xffffu);
  h[2] = (b[1] & 0xffff0000u) | (b[0] >> 16);
  l[2] = (b[1] << 16)         | (b[0] & 0xffffu);
  h[3] = (b[3] & 0xffff0000u) | (b[2] >> 16);
  l[3] = (b[3] << 16)         | (b[2] & 0xffffu);
  hi = __builtin_bit_cast(bf16x8, h);
  lo = __builtin_bit_cast(bf16x8, l);
}

#define MFMA16(a, b, c) __builtin_amdgcn_mfma_f32_16x16x32_bf16((a), (b), (c), 0, 0, 0)

// ---------------------------------------------------------------------------
// Kernel A (r21, proven): PREP_ALL = prep_x (0..575) + prep_w (576..1215) +
// cpb (1216..1224).
// ---------------------------------------------------------------------------
__global__ __launch_bounds__(256) void prep_all(
    const float* __restrict__ x,
    unsigned short* __restrict__ xph, unsigned short* __restrict__ xpl,
    const float* __restrict__ mw1, const float* __restrict__ mw2,
    const float* __restrict__ qkw, const float* __restrict__ vw,
    unsigned short* __restrict__ w1h, unsigned short* __restrict__ w1l,
    unsigned short* __restrict__ w2h, unsigned short* __restrict__ w2l,
    unsigned short* __restrict__ wqkh, unsigned short* __restrict__ wqkl,
    unsigned short* __restrict__ wvh, unsigned short* __restrict__ wvl,
    const float* __restrict__ cw1, const float* __restrict__ cb1,
    const float* __restrict__ cw2, float* __restrict__ tab) {
  __shared__ float xt[128 * 65];
  const int b = blockIdx.x;
  const int t = threadIdx.x;
  if (b < 576) {
    const int l0 = (b % 9) * 64, bs = b / 9;
    const float* xb = x + (size_t)bs * Cc * Lc;
#pragma unroll
    for (int pass = 0; pass < 8; pass++) {
      int f = pass * 1024 + t * 4;
      int c = f >> 6, ll = f & 63;
      *(float4*)(xt + c * 65 + ll) = *(const float4*)(xb + c * Lc + l0 + ll);
    }
    __syncthreads();
    const int rowl = t >> 2, c0 = (t & 3) * 32;
    const size_t p = (size_t)bs * Lc + l0 + rowl;
    unsigned short hbuf[32], lbuf[32];
#pragma unroll
    for (int i = 0; i < 32; i++) {
      float v = xt[(c0 + i) * 65 + rowl];
      unsigned short hi = f2bf(v);
      hbuf[i] = hi;
      lbuf[i] = f2bf(v - bf2f(hi));
    }
#pragma unroll
    for (int g = 0; g < 4; g++) {
      *(u16x8*)(xph + p * 128 + c0 + g * 8) = *(u16x8*)(hbuf + g * 8);
      *(u16x8*)(xpl + p * 128 + c0 + g * 8) = *(u16x8*)(lbuf + g * 8);
    }
  } else if (b < 1216) {
    int id = (b - 576) * 256 + t;
    const float* src;
    unsigned short *dh, *dl;
    int off;
    if (id < 65536)       { src = mw1; dh = w1h;  dl = w1l;  off = id; }
    else if (id < 98304)  { src = mw2; dh = w2h;  dl = w2l;  off = id - 65536; }
    else if (id < 131072) { src = qkw; dh = wqkh; dl = wqkl; off = id - 98304; }
    else if (id < 163840) { src = vw;  dh = wvh;  dl = wvl;  off = id - 131072; }
    else return;
    float v = src[off];
    unsigned short hi = f2bf(v);
    dh[off] = hi;
    dl[off] = f2bf(v - bf2f(hi));
  } else {
    int idx = (b - 1216) * 256 + t;
    if (idx >= 47 * 47) return;
    int dy = idx / 47 - 23, dx = idx % 47 - 23;
    float fy = (float)dy * (8.0f / 23.0f);
    float fx = (float)dx * (8.0f / 23.0f);
    fy = copysignf(log2f(1.0f + fabsf(fy)) * (1.0f / 3.0f), fy);
    fx = copysignf(log2f(1.0f + fabsf(fx)) * (1.0f / 3.0f), fx);
    float a0 = 0.f, a1 = 0.f;
    for (int hh = 0; hh < 128; hh++) {
      float hv = fmaxf(cw1[2 * hh] * fy + cw1[2 * hh + 1] * fx + cb1[hh], 0.f);
      a0 += cw2[hh] * hv;
      a1 += cw2[128 + hh] * hv;
    }
    tab[idx] = a0;
    tab[2209 + idx] = a1;
  }
}

// ---------------------------------------------------------------------------
// Kernel B (r21, proven): BIAS_QKV = qkv (0..1151, r18 body) + bias_mat
// (1152..4031).
// ---------------------------------------------------------------------------
__global__ __launch_bounds__(256, 4) void bias_qkv(
    const unsigned short* __restrict__ xh, const unsigned short* __restrict__ xl,
    const unsigned short* __restrict__ wqkh, const unsigned short* __restrict__ wqkl,
    const unsigned short* __restrict__ wvh, const unsigned short* __restrict__ wvl,
    unsigned short* __restrict__ qg, unsigned short* __restrict__ kg,
    unsigned short* __restrict__ vg,
    const float* __restrict__ tab, unsigned short* __restrict__ biasC) {
  __shared__ unsigned short vt[128 * 130];   // [0,16384) u16 = A staging dbuf
  const int blk = blockIdx.x;
  const int t = threadIdx.x;
  if (blk >= 1152) {
    int id = (blk - 1152) * 256 + t;
    if (id >= 737280) return;
    int id2 = id % 2560;
    int grp = id / 2560;            // ((hh*36+mt)*4+wave)
    int wave = grp & 3;
    int mt = (grp >> 2) % 36;
    int hh = grp / 144;
    int g = id2 / 512;
    int lane = (id2 >> 3) & 63;
    int k = id2 & 7;
    int e = g * 8 + k;
    unsigned short val = 0;
    if (e < 36) {
      int ln = e >> 2, r = e & 3;
      int nt = wave * 9 + ln;
      int i = mt * 16 + (lane >> 4) * 4 + r;
      int j = nt * 16 + (lane & 15);
      int yi = i / 24, xi = i - yi * 24;
      int yj = j / 24, xj = j - yj * 24;
      val = f2bf(tab[hh * 2209 + (yi - yj + 23) * 47 + (xi - xj + 23)]);
    }
    biasC[id] = val;
    return;
  }
  const int bx = blk % 288, byy = blk / 288;
  const int wv = t >> 6, lane = t & 63;
  const int quad = lane >> 4, cc = lane & 15;
  const int n0 = (wv >> 1) * 64;
  const unsigned short* Wh = (byy < 2) ? wqkh : wvh;
  const unsigned short* Wl = (byy < 2) ? wqkl : wvl;
  const int wrow0 = (byy & 1) * 128 + n0;
  f32x4 acc[4][4];
#pragma unroll
  for (int i = 0; i < 4; i++)
#pragma unroll
    for (int j = 0; j < 4; j++) acc[i][j] = (f32x4){0.f, 0.f, 0.f, 0.f};
  {
    const int srow = lane >> 3;
    const int schunk = (lane & 7) ^ srow;
    const size_t grow = (size_t)(bx * 128 + wv * 32 + srow) * 128;
    const unsigned short* asrc = (schunk < 4)
                                     ? (xh + grow + (schunk << 3))
                                     : (xl + grow + ((schunk - 4) << 3));
    unsigned short* adst = vt + wv * 2048;   // + buf*8192 + s*512
#pragma unroll
    for (int s = 0; s < 4; s++)
      __builtin_amdgcn_global_load_lds(
          (const __attribute__((address_space(1))) unsigned int*)(asrc + s * 1024),
          (__attribute__((address_space(3))) unsigned int*)(adst + s * 512),
          16, 0, 0);
    for (int kc = 0; kc < 4; kc++) {
      __syncthreads();  // stage(kc) drained & visible to all waves
      const int bufo = (kc & 1) << 13;  // *8192 u16
      bf16x8 Ah[4], Al[4], Bh[4], Bl[4];
#pragma unroll
      for (int i = 0; i < 4; i++) {
        const int row = (wv & 1) * 64 + i * 16 + cc;
        const unsigned short* ab = vt + bufo + row * 64;
        Ah[i] = *(const bf16x8*)(ab + ((quad ^ (cc & 7)) << 3));
        Al[i] = *(const bf16x8*)(ab + (((quad + 4) ^ (cc & 7)) << 3));
      }
      if (kc < 3) {  // prefetch next chunk; flies through B-loads + MFMAs
        const int nb = ((kc + 1) & 1) << 13;
#pragma unroll
        for (int s = 0; s < 4; s++)
          __builtin_amdgcn_global_load_lds(
              (const __attribute__((address_space(1))) unsigned int*)(
                  asrc + (kc + 1) * 32 + s * 1024),
              (__attribute__((address_space(3))) unsigned int*)(adst + nb +
                                                                s * 512),
              16, 0, 0);
      }
      const int kb = kc * 32 + quad * 8;
#pragma unroll
      for (int i = 0; i < 4; i++) {
        size_t br = (size_t)(wrow0 + i * 16 + cc) * 128 + kb;
        Bh[i] = *(const bf16x8*)(Wh + br);
        Bl[i] = *(const bf16x8*)(Wl + br);
      }
#pragma unroll
      for (int i = 0; i < 4; i++)
#pragma unroll
        for (int j = 0; j < 4; j++) {
          acc[i][j] = MFMA16(Ah[i], Bh[j], acc[i][j]);
          acc[i][j] = MFMA16(Al[i], Bh[j], acc[i][j]);
          acc[i][j] = MFMA16(Ah[i], Bl[j], acc[i][j]);
        }
    }
  }
  __syncthreads();  // all staged reads done; vt may be overwritten
  if (byy < 2) {
    const float sc = (byy == 0) ? 0.125f : 1.0f;
#pragma unroll
    for (int j = 0; j < 4; j++) {
      int o = n0 + j * 16 + cc;
#pragma unroll
      for (int i = 0; i < 4; i++)
#pragma unroll
        for (int r = 0; r < 4; r++) {
          int pl = (wv & 1) * 64 + i * 16 + quad * 4 + r;
          vt[pl * 130 + o] = f2bf(acc[i][j][r] * sc);
        }
    }
    __syncthreads();
    unsigned short* dst = (byy == 0) ? qg : kg;
    const int pl = t >> 1, head = t & 1;
    const int p = bx * 128 + pl;
    const int bs = p / 576, l = p - bs * 576;
    unsigned short* drow = dst + ((size_t)(bs * 2 + head) * Lc + l) * 64;
#pragma unroll
    for (int g = 0; g < 8; g++)
      *(u16x8*)(drow + g * 8) = *(const u16x8*)(vt + pl * 130 + head * 64 + g * 8);
  } else {
    const int head = byy - 2;
#pragma unroll
    for (int j = 0; j < 4; j++) {
      int d = n0 + j * 16 + cc;
#pragma unroll
      for (int i = 0; i < 4; i++)
#pragma unroll
        for (int r = 0; r < 4; r++) {
          int pl = (wv & 1) * 64 + i * 16 + quad * 4 + r;
          vt[d * 130 + pl] = f2bf(acc[i][j][r]);
        }
    }
    __syncthreads();
    const int d = t >> 1, half = (t & 1) * 64;
#pragma unroll
    for (int c8 = 0; c8 < 8; c8++) {
      int pl = half + c8 * 8;
      int p = bx * 128 + pl;
      int bs = p / 576, l = p - bs * 576;
      *(u16x8*)(vg + ((size_t)(bs * 2 + head) * VD + d) * Lc + l) =
          *(u16x8*)(vt + d * 130 + pl);
    }
  }
}

// ---------------------------------------------------------------------------
// Kernel C (r22): FUSED ATTENTION + MLP, 512 threads (8 waves).
// Waves 0-3 = head 0, waves 4-7 = head 1 — each group is the verbatim r16
// 4-wave attn (K-ring staging, NO-MAX softmax, L2-remap); two P buffers
// Pb[2] (74.2KB -> 2 blocks/CU = 16 waves/CU, same occupancy as before).
// After PV: O scaled+packed in regs (16 u32/thread); barrier retires BOTH
// P buffers; aout[32][256] packed u32 -> Pb[0] (pitch 260, the proven r13
// layout); y1 aliases Pb[1]; MLP phases (r20 bodies, A from LDS) produce
// out directly. Eliminates the 75MB aout HBM round-trip + one launch +
// mlp's A-staging latency chain. Grid 1152 (64 bs x 18 bm), XCD-remapped.
// ---------------------------------------------------------------------------
__global__ __launch_bounds__(512, 4) void attn_mlp(
    const unsigned short* __restrict__ qg,
    const unsigned short* __restrict__ kg,
    const unsigned short* __restrict__ vg,
    const unsigned short* __restrict__ biasC,
    const float* __restrict__ sa_bias,
    const unsigned short* __restrict__ w1h, const unsigned short* __restrict__ w1l,
    const float* __restrict__ b1,
    const unsigned short* __restrict__ w2h, const unsigned short* __restrict__ w2l,
    const float* __restrict__ b2, float* __restrict__ out) {
  constexpr int PP = 580;
  __shared__ __align__(16) unsigned short Pb[2][32 * PP];  // 74,240 B
  __shared__ float psum[2][4][32];
  // ---- bijective XCD remap: xcd = f&7 -> bs values xcd, xcd+8, ... ----
  const int f = blockIdx.x;
  const int g = f >> 3;
  const int bsI = (f & 7) + 8 * (g / 18);
  const int bm = g % 18;
  const int m0 = bm * 32;
  const int t = threadIdx.x;
  const int wvg = t >> 6;        // 0..7
  const int hh = wvg >> 2;       // head of this wave group
  const int wv = wvg & 3;        // wave index within group (0..3)
  const int lane = t & 63;
  const int quad = lane >> 4, c = lane & 15;
  const int c7 = c & 7;
  const int pair = bsI * 2 + hh;
  const unsigned short* qb = qg + ((size_t)pair * Lc + m0) * 64;
  const unsigned short* kb = kg + (size_t)pair * Lc * 64;
  const unsigned short* vb = vg + (size_t)pair * VD * Lc;
  unsigned short* PbH = Pb[hh];
  // ---- Q fragments for both row-tiles ----
  bf16x8 qa0[2], qa1[2];
#pragma unroll
  for (int mt = 0; mt < 2; mt++) {
    const unsigned short* qp = qb + (size_t)(mt * 16 + c) * 64 + quad * 8;
    qa0[mt] = *(const bf16x8*)qp;
    qa1[mt] = *(const bf16x8*)(qp + 32);
  }
  // ---- S init = bias ----
  f32x4 S[2][9];
#pragma unroll
  for (int mt = 0; mt < 2; mt++) {
    const unsigned short* bbase =
        biasC + ((((size_t)hh * 36 + (bm * 2 + mt)) * 4 + wv) * 5) * 512;
#pragma unroll
    for (int g2 = 0; g2 < 5; g2++) {
      u16x8 bv = *(const u16x8*)(bbase + g2 * 512 + lane * 8);
#pragma unroll
      for (int k = 0; k < 8; k++) {
        int e = g2 * 8 + k;
        if (e < 36) S[mt][e >> 2][e & 3] = bf2f(bv[k]);
      }
    }
  }
  // ---- QK with per-wave async K-staging (3-buf ring, 2 tiles ahead) ----
  {
    unsigned short* Ks = PbH + wv * 1024;  // wave region; + buf*4096 u16
    const int srow = lane >> 3;
    const unsigned short* ksrc = kb + (size_t)(wv * 144 + srow) * 64 +
                                 (((lane & 7) ^ srow) << 3);
#pragma unroll
    for (int tt = 0; tt < 2; tt++)
#pragma unroll
      for (int s = 0; s < 2; s++)
        __builtin_amdgcn_global_load_lds(
            (const __attribute__((address_space(1))) unsigned int*)(
                ksrc + tt * 1024 + s * 512),
            (__attribute__((address_space(3))) unsigned int*)(
                Ks + tt * 4096 + s * 512),
            16, 0, 0);
#pragma unroll
    for (int ln = 0; ln < 9; ln++) {
      if (ln + 2 < 9) {
        // WAR guard: ring buf (ln+2)%3 was ds_read one iteration ago.
        asm volatile("s_waitcnt lgkmcnt(0)" ::: "memory");
        __builtin_amdgcn_sched_barrier(0);
#pragma unroll
        for (int s = 0; s < 2; s++)
          __builtin_amdgcn_global_load_lds(
              (const __attribute__((address_space(1))) unsigned int*)(
                  ksrc + (ln + 2) * 1024 + s * 512),
              (__attribute__((address_space(3))) unsigned int*)(
                  Ks + ((ln + 2) % 3) * 4096 + s * 512),
              16, 0, 0);
        asm volatile("s_waitcnt vmcnt(4)" ::: "memory");  // tile ln landed
      } else if (ln == 7) {
        asm volatile("s_waitcnt vmcnt(2)" ::: "memory");
      } else {
        asm volatile("s_waitcnt vmcnt(0)" ::: "memory");
      }
      __builtin_amdgcn_sched_barrier(0);
      const unsigned short* kbuf = Ks + (ln % 3) * 4096;
      bf16x8 b0 = *(const bf16x8*)(kbuf + c * 64 + ((quad ^ c7) << 3));
      bf16x8 b1 = *(const bf16x8*)(kbuf + c * 64 + (((quad + 4) ^ c7) << 3));
#pragma unroll
      for (int mt = 0; mt < 2; mt++)
        S[mt][ln] = MFMA16(qa1[mt], b1, MFMA16(qa0[mt], b0, S[mt][ln]));
    }
  }
  __syncthreads();  // staged-K regions dead; P writes may begin
  // ---- exp (no max) + partial sums + P -> PbH ----
  float sm[2][4] = {{0.f, 0.f, 0.f, 0.f}, {0.f, 0.f, 0.f, 0.f}};
#pragma unroll
  for (int mt = 0; mt < 2; mt++)
#pragma unroll
    for (int ln = 0; ln < 9; ln++)
#pragma unroll
      for (int r = 0; r < 4; r++) {
        float e = __expf(S[mt][ln][r]);
        sm[mt][r] += e;
        PbH[(mt * 16 + quad * 4 + r) * PP + (wv * 9 + ln) * 16 + c] = f2bf(e);
      }
#pragma unroll
  for (int sh = 1; sh < 16; sh <<= 1)
#pragma unroll
    for (int mt = 0; mt < 2; mt++)
#pragma unroll
      for (int r = 0; r < 4; r++) sm[mt][r] += __shfl_xor(sm[mt][r], sh);
  if (c == 0)
#pragma unroll
    for (int mt = 0; mt < 2; mt++)
#pragma unroll
      for (int r = 0; r < 4; r++)
        psum[hh][wv][mt * 16 + quad * 4 + r] = sm[mt][r];
  __syncthreads();
  float inv[2][4];
#pragma unroll
  for (int mt = 0; mt < 2; mt++)
#pragma unroll
    for (int r = 0; r < 4; r++) {
      int row = mt * 16 + quad * 4 + r;
      inv[mt][r] = 1.0f / (psum[hh][0][row] + psum[hh][1][row] +
                           psum[hh][2][row] + psum[hh][3][row]);
    }
  // ---- PV: this wave's 2 d-chunks over all 576 cols, 2 row-tiles ----
  const int nd0 = wv * 2;
  f32x4 O[2][2];
#pragma unroll
  for (int mt = 0; mt < 2; mt++)
#pragma unroll
    for (int dd = 0; dd < 2; dd++) O[mt][dd] = (f32x4){0.f, 0.f, 0.f, 0.f};
#pragma unroll
  for (int kc = 0; kc < 18; kc++) {
    bf16x8 pa[2];
#pragma unroll
    for (int mt = 0; mt < 2; mt++)
      pa[mt] = *(const bf16x8*)(PbH + (size_t)(mt * 16 + c) * PP + kc * 32 +
                                quad * 8);
#pragma unroll
    for (int dd = 0; dd < 2; dd++) {
      bf16x8 vf = *(const bf16x8*)(vb + (size_t)((nd0 + dd) * 16 + c) * Lc +
                                   kc * 32 + quad * 8);
#pragma unroll
      for (int mt = 0; mt < 2; mt++) O[mt][dd] = MFMA16(pa[mt], vf, O[mt][dd]);
    }
  }
  // ---- scale + sa_bias + pack (registers only) ----
  unsigned int opk[2][2][4];
#pragma unroll
  for (int dd = 0; dd < 2; dd++) {
    float sb = sa_bias[hh * 128 + (nd0 + dd) * 16 + c];
#pragma unroll
    for (int mt = 0; mt < 2; mt++)
#pragma unroll
      for (int r = 0; r < 4; r++)
        opk[mt][dd][r] = packhl(O[mt][dd][r] * inv[mt][r] + sb);
  }
  __syncthreads();  // ALL waves done reading P; both Pb buffers dead
  // ---- aout[32][256] packed u32 -> Pb[0] region, pitch 260 ----
  unsigned int* aoutL = (unsigned int*)&Pb[0][0];
#pragma unroll
  for (int dd = 0; dd < 2; dd++)
#pragma unroll
    for (int mt = 0; mt < 2; mt++)
#pragma unroll
      for (int r = 0; r < 4; r++)
        aoutL[(mt * 16 + quad * 4 + r) * 260 + hh * 128 + (nd0 + dd) * 16 + c] =
            opk[mt][dd][r];
  __syncthreads();
  // ---- MLP phase 1: y1 = gelu(aout @ w1^T + b1); wave wvg -> 32x32 ----
  const int n0 = wvg * 32;
  f32x4 acc1[2][2];
#pragma unroll
  for (int i = 0; i < 2; i++)
#pragma unroll
    for (int j = 0; j < 2; j++) acc1[i][j] = (f32x4){0.f, 0.f, 0.f, 0.f};
  for (int kc = 0; kc < 8; kc++) {
    const int kbb = kc * 32 + quad * 8;
    bf16x8 Ah[2], Al[2], Bh[2], Bl[2];
#pragma unroll
    for (int i = 0; i < 2; i++) {
      const unsigned int* arow = aoutL + (i * 16 + c) * 260 + kbb;
      u32x4 pa = *(const u32x4*)arow;
      u32x4 pbv = *(const u32x4*)(arow + 4);
      unpack8(pa, pbv, Ah[i], Al[i]);
    }
#pragma unroll
    for (int j = 0; j < 2; j++) {
      size_t br = (size_t)(n0 + j * 16 + c) * HID + kbb;
      Bh[j] = *(const bf16x8*)(w1h + br);
      Bl[j] = *(const bf16x8*)(w1l + br);
    }
#pragma unroll
    for (int i = 0; i < 2; i++)
#pragma unroll
      for (int j = 0; j < 2; j++) {
        acc1[i][j] = MFMA16(Ah[i], Bh[j], acc1[i][j]);
        acc1[i][j] = MFMA16(Al[i], Bh[j], acc1[i][j]);
        acc1[i][j] = MFMA16(Ah[i], Bl[j], acc1[i][j]);
      }
  }
  // y1 -> Pb[1] region (disjoint from aoutL; PV reads already barriered)
  unsigned int* y1L = (unsigned int*)&Pb[1][0];
#pragma unroll
  for (int j = 0; j < 2; j++) {
    int col = n0 + j * 16 + c;
    float bias = b1[col];
#pragma unroll
    for (int i = 0; i < 2; i++)
#pragma unroll
      for (int r = 0; r < 4; r++) {
        int row = i * 16 + quad * 4 + r;
        float v = acc1[i][j][r] + bias;
        float ge = 0.5f * v * (1.0f + erff(v * 0.70710678118654752f));
        y1L[row * 260 + col] = packhl(ge);
      }
  }
  __syncthreads();
  // ---- MLP phase 2: out = y1 @ w2^T + b2; wave wvg -> 32x16 ----
  {
    const int n2 = wvg * 16;
    f32x4 acc2[2];
#pragma unroll
    for (int i = 0; i < 2; i++) acc2[i] = (f32x4){0.f, 0.f, 0.f, 0.f};
    for (int kc = 0; kc < 8; kc++) {
      const int kbb = kc * 32 + quad * 8;
      bf16x8 Ah[2], Al[2], Bh, Bl;
#pragma unroll
      for (int i = 0; i < 2; i++) {
        const unsigned int* arow = y1L + (i * 16 + c) * 260 + kbb;
        u32x4 pa = *(const u32x4*)arow;
        u32x4 pbv = *(const u32x4*)(arow + 4);
        unpack8(pa, pbv, Ah[i], Al[i]);
      }
      {
        size_t br = (size_t)(n2 + c) * HID + kbb;
        Bh = *(const bf16x8*)(w2h + br);
        Bl = *(const bf16x8*)(w2l + br);
      }
#pragma unroll
      for (int i = 0; i < 2; i++) {
        acc2[i] = MFMA16(Ah[i], Bh, acc2[i]);
        acc2[i] = MFMA16(Al[i], Bh, acc2[i]);
        acc2[i] = MFMA16(Ah[i], Bl, acc2[i]);
      }
    }
#pragma unroll
    for (int i = 0; i < 2; i++) {
      int l = m0 + i * 16 + quad * 4;       // 4 consecutive pixels in-image
      int col = n2 + c;
      float bias = b2[col];
      float4 v = make_float4(acc2[i][0] + bias, acc2[i][1] + bias,
                             acc2[i][2] + bias, acc2[i][3] + bias);
      *(float4*)(out + ((size_t)bsI * OUTC + col) * Lc + l) = v;
    }
  }
}

// ---------------------------------------------------------------------------
// ws layout (bytes): unchanged from r21 (aout_p region now unused).
// ---------------------------------------------------------------------------
extern "C" void kernel_launch(void* const* d_in, const int* in_sizes, int n_in,
                              void* d_out, int out_size, void* d_ws, size_t ws_size,
                              hipStream_t stream) {
  const float* x    = (const float*)d_in[0];
  const float* qk_w = (const float*)d_in[1];
  const float* v_w  = (const float*)d_in[2];
  const float* cw1  = (const float*)d_in[3];
  const float* cb1  = (const float*)d_in[4];
  const float* cw2  = (const float*)d_in[5];
  const float* sab  = (const float*)d_in[6];
  const float* mw1  = (const float*)d_in[7];
  const float* mb1  = (const float*)d_in[8];
  const float* mw2  = (const float*)d_in[9];
  const float* mb2  = (const float*)d_in[10];
  float* out = (float*)d_out;
  char* ws = (char*)d_ws;

  float* tab = (float*)(ws);
  unsigned short* biasC  = (unsigned short*)(ws + 65536);
  unsigned short* qg     = (unsigned short*)(ws + 1572864);
  unsigned short* kg     = (unsigned short*)(ws + 11010048);
  unsigned short* vg     = (unsigned short*)(ws + 20447232);
  unsigned short* xph    = (unsigned short*)(ws + 39321600);
  unsigned short* xpl    = (unsigned short*)(ws + 48758784);
  unsigned short* w1h    = (unsigned short*)(ws + 95944704);
  unsigned short* w1l    = (unsigned short*)(ws + 96075776);
  unsigned short* w2h    = (unsigned short*)(ws + 96206848);
  unsigned short* w2l    = (unsigned short*)(ws + 96272384);
  unsigned short* wqkh   = (unsigned short*)(ws + 96337920);
  unsigned short* wqkl   = (unsigned short*)(ws + 96403456);
  unsigned short* wvh    = (unsigned short*)(ws + 96468992);
  unsigned short* wvl    = (unsigned short*)(ws + 96534528);

  prep_all<<<dim3(1225), dim3(256), 0, stream>>>(
      x, xph, xpl, mw1, mw2, qk_w, v_w, w1h, w1l, w2h, w2l,
      wqkh, wqkl, wvh, wvl, cw1, cb1, cw2, tab);
  bias_qkv<<<dim3(4032), dim3(256), 0, stream>>>(
      xph, xpl, wqkh, wqkl, wvh, wvl, qg, kg, vg, tab, biasC);
  attn_mlp<<<dim3(1152), dim3(512), 0, stream>>>(
      qg, kg, vg, biasC, sab, w1h, w1l, mb1, w2h, w2l, mb2, out);
}

// Round 17
// 250.187 us; speedup vs baseline: 1.0096x; 1.0096x over previous
//
#include <hip/hip_runtime.h>
#include <cstdint>
#include <cstddef>

// Problem constants: b=2,s=32 -> BS=64; c=128; h=w=24 -> L=576
constexpr int BS   = 64;
constexpr int Cc   = 128;
constexpr int Lc   = 576;
constexpr int VD   = 128;   // v dim per head
constexpr int HID  = 256;
constexpr int OUTC = 128;
constexpr int NPIX = BS * Lc;  // 36864

typedef __bf16 bf16x8 __attribute__((ext_vector_type(8)));
typedef float  f32x4  __attribute__((ext_vector_type(4)));
typedef unsigned short u16x8 __attribute__((ext_vector_type(8)));
typedef unsigned int   u32x4 __attribute__((ext_vector_type(4)));

__device__ __forceinline__ unsigned short f2bf(float f) {
  unsigned int u = __builtin_bit_cast(unsigned int, f);
  u += 0x7fffu + ((u >> 16) & 1u);   // RTNE (inputs finite)
  return (unsigned short)(u >> 16);
}
__device__ __forceinline__ float bf2f(unsigned short h) {
  unsigned int u = ((unsigned int)h) << 16;
  return __builtin_bit_cast(float, u);
}
// pack value as hi-bf16 (bits 31:16) | lo-bf16 (bits 15:0), lo = residual
__device__ __forceinline__ unsigned int packhl(float v) {
  unsigned short hi = f2bf(v);
  unsigned short lo = f2bf(v - bf2f(hi));
  return ((unsigned int)hi << 16) | (unsigned int)lo;
}
// unpack 8 packed elements (two 16B u32x4 loads) -> hi/lo bf16x8 fragments
__device__ __forceinline__ void unpack8(u32x4 a, u32x4 b, bf16x8& hi, bf16x8& lo) {
  u32x4 h, l;
  h[0] = (a[1] & 0xffff0000u) | (a[0] >> 16);
  l[0] = (a[1] << 16)         | (a[0] & 0xffffu);
  h[1] = (a[3] & 0xffff0000u) | (a[2] >> 16);
  l[1] = (a[3] << 16)         | (a[2] & 0xffffu);
  h[2] = (b[1] & 0xffff0000u) | (b[0] >> 16);
  l[2] = (b[1] << 16)         | (b[0] & 0xffffu);
  h[3] = (b[3] & 0xffff0000u) | (b[2] >> 16);
  l[3] = (b[3] << 16)         | (b[2] & 0xffffu);
  hi = __builtin_bit_cast(bf16x8, h);
  lo = __builtin_bit_cast(bf16x8, l);
}

#define MFMA16(a, b, c) __builtin_amdgcn_mfma_f32_16x16x32_bf16((a), (b), (c), 0, 0, 0)

// ---------------------------------------------------------------------------
// Kernel A (r21, proven): PREP_ALL = prep_x (0..575) + prep_w (576..1215) +
// cpb (1216..1224).
// ---------------------------------------------------------------------------
__global__ __launch_bounds__(256) void prep_all(
    const float* __restrict__ x,
    unsigned short* __restrict__ xph, unsigned short* __restrict__ xpl,
    const float* __restrict__ mw1, const float* __restrict__ mw2,
    const float* __restrict__ qkw, const float* __restrict__ vw,
    unsigned short* __restrict__ w1h, unsigned short* __restrict__ w1l,
    unsigned short* __restrict__ w2h, unsigned short* __restrict__ w2l,
    unsigned short* __restrict__ wqkh, unsigned short* __restrict__ wqkl,
    unsigned short* __restrict__ wvh, unsigned short* __restrict__ wvl,
    const float* __restrict__ cw1, const float* __restrict__ cb1,
    const float* __restrict__ cw2, float* __restrict__ tab) {
  __shared__ float xt[128 * 65];
  const int b = blockIdx.x;
  const int t = threadIdx.x;
  if (b < 576) {
    const int l0 = (b % 9) * 64, bs = b / 9;
    const float* xb = x + (size_t)bs * Cc * Lc;
#pragma unroll
    for (int pass = 0; pass < 8; pass++) {
      int f = pass * 1024 + t * 4;
      int c = f >> 6, ll = f & 63;
      *(float4*)(xt + c * 65 + ll) = *(const float4*)(xb + c * Lc + l0 + ll);
    }
    __syncthreads();
    const int rowl = t >> 2, c0 = (t & 3) * 32;
    const size_t p = (size_t)bs * Lc + l0 + rowl;
    unsigned short hbuf[32], lbuf[32];
#pragma unroll
    for (int i = 0; i < 32; i++) {
      float v = xt[(c0 + i) * 65 + rowl];
      unsigned short hi = f2bf(v);
      hbuf[i] = hi;
      lbuf[i] = f2bf(v - bf2f(hi));
    }
#pragma unroll
    for (int g = 0; g < 4; g++) {
      *(u16x8*)(xph + p * 128 + c0 + g * 8) = *(u16x8*)(hbuf + g * 8);
      *(u16x8*)(xpl + p * 128 + c0 + g * 8) = *(u16x8*)(lbuf + g * 8);
    }
  } else if (b < 1216) {
    int id = (b - 576) * 256 + t;
    const float* src;
    unsigned short *dh, *dl;
    int off;
    if (id < 65536)       { src = mw1; dh = w1h;  dl = w1l;  off = id; }
    else if (id < 98304)  { src = mw2; dh = w2h;  dl = w2l;  off = id - 65536; }
    else if (id < 131072) { src = qkw; dh = wqkh; dl = wqkl; off = id - 98304; }
    else if (id < 163840) { src = vw;  dh = wvh;  dl = wvl;  off = id - 131072; }
    else return;
    float v = src[off];
    unsigned short hi = f2bf(v);
    dh[off] = hi;
    dl[off] = f2bf(v - bf2f(hi));
  } else {
    int idx = (b - 1216) * 256 + t;
    if (idx >= 47 * 47) return;
    int dy = idx / 47 - 23, dx = idx % 47 - 23;
    float fy = (float)dy * (8.0f / 23.0f);
    float fx = (float)dx * (8.0f / 23.0f);
    fy = copysignf(log2f(1.0f + fabsf(fy)) * (1.0f / 3.0f), fy);
    fx = copysignf(log2f(1.0f + fabsf(fx)) * (1.0f / 3.0f), fx);
    float a0 = 0.f, a1 = 0.f;
    for (int hh = 0; hh < 128; hh++) {
      float hv = fmaxf(cw1[2 * hh] * fy + cw1[2 * hh + 1] * fx + cb1[hh], 0.f);
      a0 += cw2[hh] * hv;
      a1 += cw2[128 + hh] * hv;
    }
    tab[idx] = a0;
    tab[2209 + idx] = a1;
  }
}

// ---------------------------------------------------------------------------
// Kernel B (r23): BIAS_QKV = qkv (0..1151) + bias_mat (1152..4031).
// r23 change: qkv sibling remap — the 4 by-blocks sharing one bx's A-rows
// are now TEMPORALLY ADJACENT ON THE SAME XCD (xcd=blk&7, u=blk>>3,
// bx=xcd+8*(u>>2), byy=u&3; bijective since u>>2<36 -> bx<288). Per-XCD
// unique-A working set = 36 bx x 64KB = 2.3MB -> L2-resident; A-staging
// (the barrier-synced binding chain) hits L2 (~200cy) instead of HBM
// (~900cy) for 3 of 4 sibling reads. qkv body otherwise r18, proven.
// ---------------------------------------------------------------------------
__global__ __launch_bounds__(256, 4) void bias_qkv(
    const unsigned short* __restrict__ xh, const unsigned short* __restrict__ xl,
    const unsigned short* __restrict__ wqkh, const unsigned short* __restrict__ wqkl,
    const unsigned short* __restrict__ wvh, const unsigned short* __restrict__ wvl,
    unsigned short* __restrict__ qg, unsigned short* __restrict__ kg,
    unsigned short* __restrict__ vg,
    const float* __restrict__ tab, unsigned short* __restrict__ biasC) {
  __shared__ unsigned short vt[128 * 130];   // [0,16384) u16 = A staging dbuf
  const int blk = blockIdx.x;
  const int t = threadIdx.x;
  if (blk >= 1152) {
    int id = (blk - 1152) * 256 + t;
    if (id >= 737280) return;
    int id2 = id % 2560;
    int grp = id / 2560;            // ((hh*36+mt)*4+wave)
    int wave = grp & 3;
    int mt = (grp >> 2) % 36;
    int hh = grp / 144;
    int g = id2 / 512;
    int lane = (id2 >> 3) & 63;
    int k = id2 & 7;
    int e = g * 8 + k;
    unsigned short val = 0;
    if (e < 36) {
      int ln = e >> 2, r = e & 3;
      int nt = wave * 9 + ln;
      int i = mt * 16 + (lane >> 4) * 4 + r;
      int j = nt * 16 + (lane & 15);
      int yi = i / 24, xi = i - yi * 24;
      int yj = j / 24, xj = j - yj * 24;
      val = f2bf(tab[hh * 2209 + (yi - yj + 23) * 47 + (xi - xj + 23)]);
    }
    biasC[id] = val;
    return;
  }
  // r23 sibling remap (bijective): 4 by's of one bx run back-to-back per XCD
  const int bx = (blk & 7) + 8 * ((blk >> 3) >> 2);
  const int byy = (blk >> 3) & 3;
  const int wv = t >> 6, lane = t & 63;
  const int quad = lane >> 4, cc = lane & 15;
  const int n0 = (wv >> 1) * 64;
  const unsigned short* Wh = (byy < 2) ? wqkh : wvh;
  const unsigned short* Wl = (byy < 2) ? wqkl : wvl;
  const int wrow0 = (byy & 1) * 128 + n0;
  f32x4 acc[4][4];
#pragma unroll
  for (int i = 0; i < 4; i++)
#pragma unroll
    for (int j = 0; j < 4; j++) acc[i][j] = (f32x4){0.f, 0.f, 0.f, 0.f};
  {
    const int srow = lane >> 3;
    const int schunk = (lane & 7) ^ srow;
    const size_t grow = (size_t)(bx * 128 + wv * 32 + srow) * 128;
    const unsigned short* asrc = (schunk < 4)
                                     ? (xh + grow + (schunk << 3))
                                     : (xl + grow + ((schunk - 4) << 3));
    unsigned short* adst = vt + wv * 2048;   // + buf*8192 + s*512
#pragma unroll
    for (int s = 0; s < 4; s++)
      __builtin_amdgcn_global_load_lds(
          (const __attribute__((address_space(1))) unsigned int*)(asrc + s * 1024),
          (__attribute__((address_space(3))) unsigned int*)(adst + s * 512),
          16, 0, 0);
    for (int kc = 0; kc < 4; kc++) {
      __syncthreads();  // stage(kc) drained & visible to all waves
      const int bufo = (kc & 1) << 13;  // *8192 u16
      bf16x8 Ah[4], Al[4], Bh[4], Bl[4];
#pragma unroll
      for (int i = 0; i < 4; i++) {
        const int row = (wv & 1) * 64 + i * 16 + cc;
        const unsigned short* ab = vt + bufo + row * 64;
        Ah[i] = *(const bf16x8*)(ab + ((quad ^ (cc & 7)) << 3));
        Al[i] = *(const bf16x8*)(ab + (((quad + 4) ^ (cc & 7)) << 3));
      }
      if (kc < 3) {  // prefetch next chunk; flies through B-loads + MFMAs
        const int nb = ((kc + 1) & 1) << 13;
#pragma unroll
        for (int s = 0; s < 4; s++)
          __builtin_amdgcn_global_load_lds(
              (const __attribute__((address_space(1))) unsigned int*)(
                  asrc + (kc + 1) * 32 + s * 1024),
              (__attribute__((address_space(3))) unsigned int*)(adst + nb +
                                                                s * 512),
              16, 0, 0);
      }
      const int kb = kc * 32 + quad * 8;
#pragma unroll
      for (int i = 0; i < 4; i++) {
        size_t br = (size_t)(wrow0 + i * 16 + cc) * 128 + kb;
        Bh[i] = *(const bf16x8*)(Wh + br);
        Bl[i] = *(const bf16x8*)(Wl + br);
      }
#pragma unroll
      for (int i = 0; i < 4; i++)
#pragma unroll
        for (int j = 0; j < 4; j++) {
          acc[i][j] = MFMA16(Ah[i], Bh[j], acc[i][j]);
          acc[i][j] = MFMA16(Al[i], Bh[j], acc[i][j]);
          acc[i][j] = MFMA16(Ah[i], Bl[j], acc[i][j]);
        }
    }
  }
  __syncthreads();  // all staged reads done; vt may be overwritten
  if (byy < 2) {
    const float sc = (byy == 0) ? 0.125f : 1.0f;
#pragma unroll
    for (int j = 0; j < 4; j++) {
      int o = n0 + j * 16 + cc;
#pragma unroll
      for (int i = 0; i < 4; i++)
#pragma unroll
        for (int r = 0; r < 4; r++) {
          int pl = (wv & 1) * 64 + i * 16 + quad * 4 + r;
          vt[pl * 130 + o] = f2bf(acc[i][j][r] * sc);
        }
    }
    __syncthreads();
    unsigned short* dst = (byy == 0) ? qg : kg;
    const int pl = t >> 1, head = t & 1;
    const int p = bx * 128 + pl;
    const int bs = p / 576, l = p - bs * 576;
    unsigned short* drow = dst + ((size_t)(bs * 2 + head) * Lc + l) * 64;
#pragma unroll
    for (int g = 0; g < 8; g++)
      *(u16x8*)(drow + g * 8) = *(const u16x8*)(vt + pl * 130 + head * 64 + g * 8);
  } else {
    const int head = byy - 2;
#pragma unroll
    for (int j = 0; j < 4; j++) {
      int d = n0 + j * 16 + cc;
#pragma unroll
      for (int i = 0; i < 4; i++)
#pragma unroll
        for (int r = 0; r < 4; r++) {
          int pl = (wv & 1) * 64 + i * 16 + quad * 4 + r;
          vt[d * 130 + pl] = f2bf(acc[i][j][r]);
        }
    }
    __syncthreads();
    const int d = t >> 1, half = (t & 1) * 64;
#pragma unroll
    for (int c8 = 0; c8 < 8; c8++) {
      int pl = half + c8 * 8;
      int p = bx * 128 + pl;
      int bs = p / 576, l = p - bs * 576;
      *(u16x8*)(vg + ((size_t)(bs * 2 + head) * VD + d) * Lc + l) =
          *(u16x8*)(vt + d * 130 + pl);
    }
  }
}

// ---------------------------------------------------------------------------
// Kernel 3 (r16, proven): MFMA attention, M=32 rows/block.
// (a) pair-sequential XCD remap (L2 working set ~0.9MB/XCD).
// (b) race-fixed per-wave K-ring staging (3-deep, counted vmcnt, lgkmcnt(0)
//     WAR guard before each prefetch).
// NO-MAX softmax. ONE barrier after QK separates staging/P lifetimes.
// ---------------------------------------------------------------------------
__global__ __launch_bounds__(256, 4) void attn_kernel(
    const unsigned short* __restrict__ qg,
    const unsigned short* __restrict__ kg,
    const unsigned short* __restrict__ vg,
    const unsigned short* __restrict__ biasC,
    const float* __restrict__ sa_bias,
    unsigned int* __restrict__ aout_p) {
  constexpr int PP = 580;  // row pitch (u16): 2-way bank aliasing only (free)
  __shared__ unsigned short Pb[32 * PP];          // 37,120 B -> 4 blocks/CU
  __shared__ float psum[4][32];
  // ---- pair-sequential XCD remap (bijective; XCD = blockID % 8) ----
  const int f = blockIdx.x;
  const int g = f >> 3;
  const int pair = (f & 7) + 8 * (g / 18);  // pairs of this XCD, sequential
  const int bm = g % 18;
  const int hh = pair & 1, bs = pair >> 1;
  const int m0 = bm * 32;
  const int t = threadIdx.x;
  const int wv = t >> 6, lane = t & 63;
  const int quad = lane >> 4, c = lane & 15;
  const int c7 = c & 7;
  const unsigned short* qb = qg + ((size_t)pair * Lc + m0) * 64;
  const unsigned short* kb = kg + (size_t)pair * Lc * 64;
  const unsigned short* vb = vg + (size_t)pair * VD * Lc;
  // ---- Q fragments for both row-tiles ----
  bf16x8 qa0[2], qa1[2];
#pragma unroll
  for (int mt = 0; mt < 2; mt++) {
    const unsigned short* qp = qb + (size_t)(mt * 16 + c) * 64 + quad * 8;
    qa0[mt] = *(const bf16x8*)qp;
    qa1[mt] = *(const bf16x8*)(qp + 32);
  }
  // ---- S init = bias (10 coalesced 16B loads/lane, 2 row-tiles) ----
  f32x4 S[2][9];
#pragma unroll
  for (int mt = 0; mt < 2; mt++) {
    const unsigned short* bbase =
        biasC + ((((size_t)hh * 36 + (bm * 2 + mt)) * 4 + wv) * 5) * 512;
#pragma unroll
    for (int g2 = 0; g2 < 5; g2++) {
      u16x8 bv = *(const u16x8*)(bbase + g2 * 512 + lane * 8);
#pragma unroll
      for (int k = 0; k < 8; k++) {
        int e = g2 * 8 + k;
        if (e < 36) S[mt][e >> 2][e & 3] = bf2f(bv[k]);
      }
    }
  }
  // ---- QK with per-wave async K-staging (3-buf ring, 2 tiles ahead) ----
  {
    unsigned short* Ks = Pb + wv * 1024;  // wave region; + buf*4096 u16
    const int srow = lane >> 3;
    const unsigned short* ksrc = kb + (size_t)(wv * 144 + srow) * 64 +
                                 (((lane & 7) ^ srow) << 3);
#pragma unroll
    for (int tt = 0; tt < 2; tt++)
#pragma unroll
      for (int s = 0; s < 2; s++)
        __builtin_amdgcn_global_load_lds(
            (const __attribute__((address_space(1))) unsigned int*)(
                ksrc + tt * 1024 + s * 512),
            (__attribute__((address_space(3))) unsigned int*)(
                Ks + tt * 4096 + s * 512),
            16, 0, 0);
#pragma unroll
    for (int ln = 0; ln < 9; ln++) {
      if (ln + 2 < 9) {
        // WAR guard (r14 bug fix): buffer (ln+2)%3 == (ln-1)%3 was ds_read
        // one iteration ago; its reads must COMPLETE before the overwrite.
        asm volatile("s_waitcnt lgkmcnt(0)" ::: "memory");
        __builtin_amdgcn_sched_barrier(0);
#pragma unroll
        for (int s = 0; s < 2; s++)
          __builtin_amdgcn_global_load_lds(
              (const __attribute__((address_space(1))) unsigned int*)(
                  ksrc + (ln + 2) * 1024 + s * 512),
              (__attribute__((address_space(3))) unsigned int*)(
                  Ks + ((ln + 2) % 3) * 4096 + s * 512),
              16, 0, 0);
        asm volatile("s_waitcnt vmcnt(4)" ::: "memory");  // tile ln landed
      } else if (ln == 7) {
        asm volatile("s_waitcnt vmcnt(2)" ::: "memory");
      } else {
        asm volatile("s_waitcnt vmcnt(0)" ::: "memory");
      }
      __builtin_amdgcn_sched_barrier(0);
      const unsigned short* kbuf = Ks + (ln % 3) * 4096;
      bf16x8 b0 = *(const bf16x8*)(kbuf + c * 64 + ((quad ^ c7) << 3));
      bf16x8 b1 = *(const bf16x8*)(kbuf + c * 64 + (((quad + 4) ^ c7) << 3));
#pragma unroll
      for (int mt = 0; mt < 2; mt++)
        S[mt][ln] = MFMA16(qa1[mt], b1, MFMA16(qa0[mt], b0, S[mt][ln]));
    }
  }
  __syncthreads();  // staged-K region (Pb rows 0..23) may now be overwritten
  // ---- exp (no max) + partial sums + P -> shared LDS ----
  float sm[2][4] = {{0.f, 0.f, 0.f, 0.f}, {0.f, 0.f, 0.f, 0.f}};
#pragma unroll
  for (int mt = 0; mt < 2; mt++)
#pragma unroll
    for (int ln = 0; ln < 9; ln++)
#pragma unroll
      for (int r = 0; r < 4; r++) {
        float e = __expf(S[mt][ln][r]);
        sm[mt][r] += e;
        Pb[(mt * 16 + quad * 4 + r) * PP + (wv * 9 + ln) * 16 + c] = f2bf(e);
      }
#pragma unroll
  for (int sh = 1; sh < 16; sh <<= 1)
#pragma unroll
    for (int mt = 0; mt < 2; mt++)
#pragma unroll
      for (int r = 0; r < 4; r++) sm[mt][r] += __shfl_xor(sm[mt][r], sh);
  if (c == 0)
#pragma unroll
    for (int mt = 0; mt < 2; mt++)
#pragma unroll
      for (int r = 0; r < 4; r++)
        psum[wv][mt * 16 + quad * 4 + r] = sm[mt][r];
  __syncthreads();
  float inv[2][4];
#pragma unroll
  for (int mt = 0; mt < 2; mt++)
#pragma unroll
    for (int r = 0; r < 4; r++) {
      int row = mt * 16 + quad * 4 + r;
      inv[mt][r] =
          1.0f / (psum[0][row] + psum[1][row] + psum[2][row] + psum[3][row]);
    }
  // ---- PV: this wave's 2 d-chunks over all 576 cols, 2 row-tiles
  //      (72 MFMAs), each V fragment reused by 2 MFMAs ----
  const int nd0 = wv * 2;
  f32x4 O[2][2];
#pragma unroll
  for (int mt = 0; mt < 2; mt++)
#pragma unroll
    for (int dd = 0; dd < 2; dd++) O[mt][dd] = (f32x4){0.f, 0.f, 0.f, 0.f};
#pragma unroll
  for (int kc = 0; kc < 18; kc++) {
    bf16x8 pa[2];
#pragma unroll
    for (int mt = 0; mt < 2; mt++)
      pa[mt] = *(const bf16x8*)(Pb + (size_t)(mt * 16 + c) * PP + kc * 32 +
                                quad * 8);
#pragma unroll
    for (int dd = 0; dd < 2; dd++) {
      bf16x8 vf = *(const bf16x8*)(vb + (size_t)((nd0 + dd) * 16 + c) * Lc +
                                   kc * 32 + quad * 8);
#pragma unroll
      for (int mt = 0; mt < 2; mt++) O[mt][dd] = MFMA16(pa[mt], vf, O[mt][dd]);
    }
  }
  // ---- epilogue: O/sum + sa_bias -> aout packed u32 [p][256] ----
  unsigned int* obp = aout_p + ((size_t)bs * Lc + m0) * HID + hh * 128;
#pragma unroll
  for (int dd = 0; dd < 2; dd++) {
    float sb = sa_bias[hh * 128 + (nd0 + dd) * 16 + c];
#pragma unroll
    for (int mt = 0; mt < 2; mt++)
#pragma unroll
      for (int r = 0; r < 4; r++) {
        float v = O[mt][dd][r] * inv[mt][r] + sb;
        obp[(size_t)(mt * 16 + quad * 4 + r) * HID + (nd0 + dd) * 16 + c] =
            packhl(v);
      }
  }
}

// ---------------------------------------------------------------------------
// Kernel 4 (r20, proven): FUSED MLP, M=32/block — counted-vmcnt phase-1.
// B(kc) loads -> stage(kc+1) into 3-deep ring -> vmcnt(9/8) -> raw s_barrier
// -> ds_read buf(kc%3) -> MFMAs. Distance-2 WAR by construction.
// y1 pitch-260 aliases the ring; __syncthreads separates lifetimes.
// 33,280B, 4 blocks/CU, grid 1152.
// ---------------------------------------------------------------------------
__global__ __launch_bounds__(256, 4) void mlp_fused(
    const unsigned int* __restrict__ ap,
    const unsigned short* __restrict__ w1h, const unsigned short* __restrict__ w1l,
    const float* __restrict__ b1,
    const unsigned short* __restrict__ w2h, const unsigned short* __restrict__ w2l,
    const float* __restrict__ b2, float* __restrict__ out) {
  constexpr int YPW = 260;                // y1 pitch in u32 words
  __shared__ unsigned int lds[32 * YPW];  // 33,280 B; words [0,3072) = A ring
  const int t = threadIdx.x;
  const int wv = t >> 6, lane = t & 63;
  const int quad = lane >> 4, cc = lane & 15;
  const int c7 = cc & 7;
  const int M0 = blockIdx.x * 32;

  // lane covers row 8*wv + lane/8, slot lane&7 = chunk (lane&7)^(row&7)
  const unsigned int* gsrc = ap + (size_t)(M0 + 8 * wv + (lane >> 3)) * HID +
                             (((lane & 7) ^ (lane >> 3)) << 2);
  // prologue: stage chunk 0 -> ring buf 0
  __builtin_amdgcn_global_load_lds(
      (const __attribute__((address_space(1))) unsigned int*)gsrc,
      (__attribute__((address_space(3))) unsigned int*)(&lds[wv * 256]),
      16, 0, 0);

  const int n0 = wv * 64;
  f32x4 acc1[2][4];
#pragma unroll
  for (int i = 0; i < 2; i++)
#pragma unroll
    for (int j = 0; j < 4; j++) acc1[i][j] = (f32x4){0.f, 0.f, 0.f, 0.f};
#pragma unroll
  for (int kc = 0; kc < 8; kc++) {
    // ---- B(kc) loads (independent of staging; counted in the wait) ----
    const int kb = kc * 32 + quad * 8;
    bf16x8 Bh[4], Bl[4];
#pragma unroll
    for (int j = 0; j < 4; j++) {
      size_t br = (size_t)(n0 + j * 16 + cc) * HID + kb;
      Bh[j] = *(const bf16x8*)(w1h + br);
      Bl[j] = *(const bf16x8*)(w1l + br);
    }
    // ---- issue stage(kc+1) into ring buf (kc+1)%3 (readers ran at kc-2) ----
    if (kc < 7) {
      __builtin_amdgcn_global_load_lds(
          (const __attribute__((address_space(1))) unsigned int*)(gsrc +
                                                                  (kc + 1) * 32),
          (__attribute__((address_space(3))) unsigned int*)(
              &lds[(((kc + 1) % 3) << 10) + wv * 256]),
          16, 0, 0);
    }
    __builtin_amdgcn_sched_barrier(0);
    // stage(kc) landed: 8 B(kc) + 1 stage(kc+1) are the only newer VMEM ops
    if (kc < 7) asm volatile("s_waitcnt vmcnt(9)" ::: "memory");
    else        asm volatile("s_waitcnt vmcnt(8)" ::: "memory");
    __builtin_amdgcn_sched_barrier(0);
    __builtin_amdgcn_s_barrier();  // all waves' stage(kc) landed; no drain
    __builtin_amdgcn_sched_barrier(0);
    const int bufw = (kc % 3) << 10;
    bf16x8 Ah[2], Al[2];
#pragma unroll
    for (int i = 0; i < 2; i++) {
      const int row = i * 16 + cc;
      u32x4 pa = *(const u32x4*)&lds[bufw + row * 32 + (((2 * quad) ^ c7) << 2)];
      u32x4 pb =
          *(const u32x4*)&lds[bufw + row * 32 + (((2 * quad + 1) ^ c7) << 2)];
      unpack8(pa, pb, Ah[i], Al[i]);
    }
#pragma unroll
    for (int i = 0; i < 2; i++)
#pragma unroll
      for (int j = 0; j < 4; j++) {
        acc1[i][j] = MFMA16(Ah[i], Bh[j], acc1[i][j]);
        acc1[i][j] = MFMA16(Al[i], Bh[j], acc1[i][j]);
        acc1[i][j] = MFMA16(Ah[i], Bl[j], acc1[i][j]);
      }
  }
  __syncthreads();  // full drain: all waves done reading the A ring
  // ---- y1 (GELU'd, packed u32) -> LDS pitch 260 ----
#pragma unroll
  for (int j = 0; j < 4; j++) {
    int col = n0 + j * 16 + cc;
    float bias = b1[col];
#pragma unroll
    for (int i = 0; i < 2; i++)
#pragma unroll
      for (int r = 0; r < 4; r++) {
        int row = i * 16 + quad * 4 + r;  // block-local row 0..31
        float v = acc1[i][j][r] + bias;
        float g = 0.5f * v * (1.0f + erff(v * 0.70710678118654752f));
        lds[row * YPW + col] = packhl(g);
      }
  }
  __syncthreads();
  // ---- phase 2: out = y1 @ w2^T + b2; wave wv -> 32 x 32 n-slice ----
  {
    const int n2 = wv * 32;
    f32x4 acc2[2][2];
#pragma unroll
    for (int i = 0; i < 2; i++)
#pragma unroll
      for (int j = 0; j < 2; j++) acc2[i][j] = (f32x4){0.f, 0.f, 0.f, 0.f};
    for (int kc = 0; kc < 8; kc++) {
      const int kb = kc * 32 + quad * 8;
      bf16x8 Ah[2], Al[2], Bh[2], Bl[2];
#pragma unroll
      for (int i = 0; i < 2; i++) {
        const unsigned int* arow = &lds[(i * 16 + cc) * YPW + kb];
        u32x4 pa = *(const u32x4*)arow;
        u32x4 pb = *(const u32x4*)(arow + 4);
        unpack8(pa, pb, Ah[i], Al[i]);
      }
#pragma unroll
      for (int j = 0; j < 2; j++) {
        size_t br = (size_t)(n2 + j * 16 + cc) * HID + kb;
        Bh[j] = *(const bf16x8*)(w2h + br);
        Bl[j] = *(const bf16x8*)(w2l + br);
      }
#pragma unroll
      for (int i = 0; i < 2; i++)
#pragma unroll
        for (int j = 0; j < 2; j++) {
          acc2[i][j] = MFMA16(Ah[i], Bh[j], acc2[i][j]);
          acc2[i][j] = MFMA16(Al[i], Bh[j], acc2[i][j]);
          acc2[i][j] = MFMA16(Ah[i], Bl[j], acc2[i][j]);
        }
    }
#pragma unroll
    for (int i = 0; i < 2; i++) {
      int p = M0 + i * 16 + quad * 4;      // 4 consecutive pixels
      int bs = p / Lc, l = p - bs * Lc;    // never straddles (4 | 576)
#pragma unroll
      for (int j = 0; j < 2; j++) {
        int col = n2 + j * 16 + cc;
        float bias = b2[col];
        float4 v = make_float4(acc2[i][j][0] + bias, acc2[i][j][1] + bias,
                               acc2[i][j][2] + bias, acc2[i][j][3] + bias);
        *(float4*)(out + ((size_t)bs * OUTC + col) * Lc + l) = v;
      }
    }
  }
}

// ---------------------------------------------------------------------------
// ws layout (bytes): as r21.
// ---------------------------------------------------------------------------
extern "C" void kernel_launch(void* const* d_in, const int* in_sizes, int n_in,
                              void* d_out, int out_size, void* d_ws, size_t ws_size,
                              hipStream_t stream) {
  const float* x    = (const float*)d_in[0];
  const float* qk_w = (const float*)d_in[1];
  const float* v_w  = (const float*)d_in[2];
  const float* cw1  = (const float*)d_in[3];
  const float* cb1  = (const float*)d_in[4];
  const float* cw2  = (const float*)d_in[5];
  const float* sab  = (const float*)d_in[6];
  const float* mw1  = (const float*)d_in[7];
  const float* mb1  = (const float*)d_in[8];
  const float* mw2  = (const float*)d_in[9];
  const float* mb2  = (const float*)d_in[10];
  float* out = (float*)d_out;
  char* ws = (char*)d_ws;

  float* tab = (float*)(ws);
  unsigned short* biasC  = (unsigned short*)(ws + 65536);
  unsigned short* qg     = (unsigned short*)(ws + 1572864);
  unsigned short* kg     = (unsigned short*)(ws + 11010048);
  unsigned short* vg     = (unsigned short*)(ws + 20447232);
  unsigned short* xph    = (unsigned short*)(ws + 39321600);
  unsigned short* xpl    = (unsigned short*)(ws + 48758784);
  unsigned int*   aout_p = (unsigned int*)(ws + 58195968);
  unsigned short* w1h    = (unsigned short*)(ws + 95944704);
  unsigned short* w1l    = (unsigned short*)(ws + 96075776);
  unsigned short* w2h    = (unsigned short*)(ws + 96206848);
  unsigned short* w2l    = (unsigned short*)(ws + 96272384);
  unsigned short* wqkh   = (unsigned short*)(ws + 96337920);
  unsigned short* wqkl   = (unsigned short*)(ws + 96403456);
  unsigned short* wvh    = (unsigned short*)(ws + 96468992);
  unsigned short* wvl    = (unsigned short*)(ws + 96534528);

  prep_all<<<dim3(1225), dim3(256), 0, stream>>>(
      x, xph, xpl, mw1, mw2, qk_w, v_w, w1h, w1l, w2h, w2l,
      wqkh, wqkl, wvh, wvl, cw1, cb1, cw2, tab);
  bias_qkv<<<dim3(4032), dim3(256), 0, stream>>>(
      xph, xpl, wqkh, wqkl, wvh, wvl, qg, kg, vg, tab, biasC);
  attn_kernel<<<dim3(2304), dim3(256), 0, stream>>>(qg, kg, vg, biasC, sab,
                                                    aout_p);
  mlp_fused<<<dim3(1152), dim3(256), 0, stream>>>(aout_p, w1h, w1l, mb1,
                                                  w2h, w2l, mb2, out);
}